// Round 1
// baseline (643.666 us; speedup 1.0000x reference)
//
#include <hip/hip_runtime.h>
#include <math.h>

#define N_NODES 50000
#define N_EDGES 800000

// ---------------- CSR build ----------------

__global__ void count_kernel(const int* __restrict__ dst, int* __restrict__ counts, int n_edges) {
    int e = blockIdx.x * blockDim.x + threadIdx.x;
    if (e < n_edges) atomicAdd(&counts[dst[e]], 1);
}

// Per-256-block exclusive scan; also emits block totals. Reused (grid=1) for the
// block-sums pass since NB=196 <= 256.
__global__ void scan_blocks(const int* __restrict__ in, int* __restrict__ out,
                            int* __restrict__ blocksums, int n) {
    int t = threadIdx.x;
    int i = blockIdx.x * 256 + t;
    int v = (i < n) ? in[i] : 0;
    int lane = t & 63, w = t >> 6;
    int sc = v;
    #pragma unroll
    for (int o = 1; o < 64; o <<= 1) {
        int u = __shfl_up(sc, o, 64);
        if (lane >= o) sc += u;
    }
    __shared__ int wsum[4];
    if (lane == 63) wsum[w] = sc;
    __syncthreads();
    int add = 0;
    #pragma unroll
    for (int j = 0; j < 4; ++j) if (j < w) add += wsum[j];
    if (i < n) out[i] = add + sc - v;             // exclusive, block-local
    if (t == 255 && blocksums) blocksums[blockIdx.x] = add + sc;  // block total
}

__global__ void scan_add(int* __restrict__ offsets, const int* __restrict__ blockoffs,
                         int* __restrict__ cursor, int n, int total) {
    int i = blockIdx.x * blockDim.x + threadIdx.x;
    if (i < n) {
        int v = offsets[i] + blockoffs[i >> 8];
        offsets[i] = v;
        cursor[i] = v;
    }
    if (i == n) offsets[n] = total;
}

__global__ void fill_kernel(const int* __restrict__ src, const int* __restrict__ dst,
                            const float* __restrict__ ew, int* __restrict__ cursor,
                            int2* __restrict__ esrt, int n_edges) {
    int e = blockIdx.x * blockDim.x + threadIdx.x;
    if (e < n_edges) {
        int p = atomicAdd(&cursor[dst[e]], 1);
        esrt[p] = make_int2(src[e], __float_as_int(ew[e]));
    }
}

// ---------------- aggregation: one wave per dst node, lane = feature ----------------

template <int DIN>
__global__ void gather_aggr(const int* __restrict__ offs, const int2* __restrict__ esrt,
                            const float* __restrict__ x, float* __restrict__ aggr) {
    int wid = (blockIdx.x * blockDim.x + threadIdx.x) >> 6;
    int lane = threadIdx.x & 63;
    if (wid >= N_NODES) return;
    int beg = offs[wid], end = offs[wid + 1];
    float acc = 0.f;
    for (int i = beg; i < end; ++i) {
        int2 e = esrt[i];  // wave-uniform broadcast load
        if (lane < DIN)
            acc += __int_as_float(e.y) * x[(size_t)e.x * DIN + lane];
    }
    if (lane < DIN) aggr[(size_t)wid * DIN + lane] = acc;
}

// ---------------- fused dual-GEMM + bias + relu ----------------
// hout[r][c] = relu(b[c] + sum_k aggr[r][k]*Wrel[k][c] + sum_k hin[r][k]*Wroot[k][c])
// One thread per row, 64 fp32 accumulators; W staged in LDS, read as broadcast float4.

template <int DIN, bool RELU>
__global__ void layer_gemm(const float* __restrict__ aggr, const float* __restrict__ hin,
                           const float* __restrict__ Wrel, const float* __restrict__ bias,
                           const float* __restrict__ Wroot, float* __restrict__ hout) {
    __shared__ float w[2 * DIN * 64 + 64];  // [Wrel | Wroot | bias]
    for (int i = threadIdx.x; i < DIN * 64; i += blockDim.x) w[i] = Wrel[i];
    for (int i = threadIdx.x; i < DIN * 64; i += blockDim.x) w[DIN * 64 + i] = Wroot[i];
    if (threadIdx.x < 64) w[2 * DIN * 64 + threadIdx.x] = bias[threadIdx.x];
    __syncthreads();

    int r = blockIdx.x * blockDim.x + threadIdx.x;
    if (r >= N_NODES) return;

    float acc[64];
    #pragma unroll
    for (int c = 0; c < 64; ++c) acc[c] = w[2 * DIN * 64 + c];

    if constexpr (DIN % 4 == 0) {
        const float4* arow = (const float4*)(aggr + (size_t)r * DIN);
        for (int k4 = 0; k4 < DIN / 4; ++k4) {
            float4 av = arow[k4];
            float a[4] = {av.x, av.y, av.z, av.w};
            #pragma unroll
            for (int kk = 0; kk < 4; ++kk) {
                const float4* wr = (const float4*)&w[(4 * k4 + kk) * 64];
                #pragma unroll
                for (int c4 = 0; c4 < 16; ++c4) {
                    float4 wv = wr[c4];
                    acc[4 * c4 + 0] += a[kk] * wv.x;
                    acc[4 * c4 + 1] += a[kk] * wv.y;
                    acc[4 * c4 + 2] += a[kk] * wv.z;
                    acc[4 * c4 + 3] += a[kk] * wv.w;
                }
            }
        }
        const float4* hrow = (const float4*)(hin + (size_t)r * DIN);
        for (int k4 = 0; k4 < DIN / 4; ++k4) {
            float4 hv = hrow[k4];
            float a[4] = {hv.x, hv.y, hv.z, hv.w};
            #pragma unroll
            for (int kk = 0; kk < 4; ++kk) {
                const float4* wr = (const float4*)&w[DIN * 64 + (4 * k4 + kk) * 64];
                #pragma unroll
                for (int c4 = 0; c4 < 16; ++c4) {
                    float4 wv = wr[c4];
                    acc[4 * c4 + 0] += a[kk] * wv.x;
                    acc[4 * c4 + 1] += a[kk] * wv.y;
                    acc[4 * c4 + 2] += a[kk] * wv.z;
                    acc[4 * c4 + 3] += a[kk] * wv.w;
                }
            }
        }
    } else {
        for (int k = 0; k < DIN; ++k) {
            float a = aggr[(size_t)r * DIN + k];
            const float4* wr = (const float4*)&w[k * 64];
            #pragma unroll
            for (int c4 = 0; c4 < 16; ++c4) {
                float4 wv = wr[c4];
                acc[4 * c4 + 0] += a * wv.x;
                acc[4 * c4 + 1] += a * wv.y;
                acc[4 * c4 + 2] += a * wv.z;
                acc[4 * c4 + 3] += a * wv.w;
            }
        }
        for (int k = 0; k < DIN; ++k) {
            float a = hin[(size_t)r * DIN + k];
            const float4* wr = (const float4*)&w[DIN * 64 + k * 64];
            #pragma unroll
            for (int c4 = 0; c4 < 16; ++c4) {
                float4 wv = wr[c4];
                acc[4 * c4 + 0] += a * wv.x;
                acc[4 * c4 + 1] += a * wv.y;
                acc[4 * c4 + 2] += a * wv.z;
                acc[4 * c4 + 3] += a * wv.w;
            }
        }
    }

    float4* outp = (float4*)(hout + (size_t)r * 64);
    #pragma unroll
    for (int c4 = 0; c4 < 16; ++c4) {
        float4 o;
        o.x = RELU ? fmaxf(acc[4 * c4 + 0], 0.f) : acc[4 * c4 + 0];
        o.y = RELU ? fmaxf(acc[4 * c4 + 1], 0.f) : acc[4 * c4 + 1];
        o.z = RELU ? fmaxf(acc[4 * c4 + 2], 0.f) : acc[4 * c4 + 2];
        o.w = RELU ? fmaxf(acc[4 * c4 + 3], 0.f) : acc[4 * c4 + 3];
        outp[c4] = o;
    }
}

// ---------------- final layer: z = h@Wrel4, root = h@Wroot4 (both [N,1]) ----------------

__global__ void final_dots(const float* __restrict__ h, const float* __restrict__ Wrel4,
                           const float* __restrict__ Wroot4, float* __restrict__ z,
                           float* __restrict__ root) {
    __shared__ float wr[64], wo[64];
    if (threadIdx.x < 64) {
        wr[threadIdx.x] = Wrel4[threadIdx.x];
        wo[threadIdx.x] = Wroot4[threadIdx.x];
    }
    __syncthreads();
    int r = blockIdx.x * blockDim.x + threadIdx.x;
    if (r >= N_NODES) return;
    const float4* hrow = (const float4*)(h + (size_t)r * 64);
    float zz = 0.f, rr = 0.f;
    #pragma unroll
    for (int k4 = 0; k4 < 16; ++k4) {
        float4 hv = hrow[k4];
        zz += hv.x * wr[4 * k4 + 0] + hv.y * wr[4 * k4 + 1] + hv.z * wr[4 * k4 + 2] + hv.w * wr[4 * k4 + 3];
        rr += hv.x * wo[4 * k4 + 0] + hv.y * wo[4 * k4 + 1] + hv.z * wo[4 * k4 + 2] + hv.w * wo[4 * k4 + 3];
    }
    z[r] = zz;
    root[r] = rr;
}

__global__ void final_aggr(const int* __restrict__ offs, const int2* __restrict__ esrt,
                           const float* __restrict__ z, const float* __restrict__ root,
                           const float* __restrict__ b4, float* __restrict__ out) {
    int d = blockIdx.x * blockDim.x + threadIdx.x;
    if (d >= N_NODES) return;
    float a = 0.f;
    int beg = offs[d], end = offs[d + 1];
    for (int i = beg; i < end; ++i) {
        int2 e = esrt[i];
        a += __int_as_float(e.y) * z[e.x];
    }
    float v = a + b4[0] + root[d];
    out[d] = 1.f / (1.f + expf(-v));
}

// ---------------- launch ----------------

extern "C" void kernel_launch(void* const* d_in, const int* in_sizes, int n_in,
                              void* d_out, int out_size, void* d_ws, size_t ws_size,
                              hipStream_t stream) {
    const float* x = (const float*)d_in[0];
    const int* eidx = (const int*)d_in[1];
    const float* ew = (const float*)d_in[2];
    const float* Wrel[5];
    const float* brel[5];
    const float* Wroot[5];
    for (int i = 0; i < 5; ++i) {
        Wrel[i] = (const float*)d_in[3 + 3 * i];
        brel[i] = (const float*)d_in[4 + 3 * i];
        Wroot[i] = (const float*)d_in[5 + 3 * i];
    }
    const int* src = eidx;
    const int* dst = eidx + N_EDGES;
    float* out = (float*)d_out;

    char* ws = (char*)d_ws;
    size_t off = 0;
    auto alloc = [&](size_t bytes) -> void* {
        void* p = ws + off;
        off = (off + bytes + 255) & ~(size_t)255;
        return p;
    };
    int* counts = (int*)alloc(N_NODES * 4);
    int* offsets = (int*)alloc((N_NODES + 1) * 4);
    int* cursor = (int*)alloc(N_NODES * 4);
    int* blocksums = (int*)alloc(256 * 4);
    int* blockoffs = (int*)alloc(256 * 4);
    int2* esrt = (int2*)alloc((size_t)N_EDGES * 8);
    float* aggr0 = (float*)alloc((size_t)N_NODES * 13 * 4);
    float* h0 = (float*)alloc((size_t)N_NODES * 64 * 4);
    float* h1 = (float*)alloc((size_t)N_NODES * 64 * 4);
    float* aggr = (float*)alloc((size_t)N_NODES * 64 * 4);
    float* z = (float*)alloc(N_NODES * 4);
    float* root = (float*)alloc(N_NODES * 4);
    (void)ws_size; (void)in_sizes; (void)n_in; (void)out_size;

    // CSR build
    hipMemsetAsync(counts, 0, N_NODES * 4, stream);
    count_kernel<<<(N_EDGES + 255) / 256, 256, 0, stream>>>(dst, counts, N_EDGES);
    const int NB = (N_NODES + 255) / 256;  // 196
    scan_blocks<<<NB, 256, 0, stream>>>(counts, offsets, blocksums, N_NODES);
    scan_blocks<<<1, 256, 0, stream>>>(blocksums, blockoffs, nullptr, NB);
    scan_add<<<(N_NODES + 1 + 255) / 256, 256, 0, stream>>>(offsets, blockoffs, cursor, N_NODES, N_EDGES);
    fill_kernel<<<(N_EDGES + 255) / 256, 256, 0, stream>>>(src, dst, ew, cursor, esrt, N_EDGES);

    // layer 0 (din=13)
    gather_aggr<13><<<(N_NODES * 64 + 255) / 256, 256, 0, stream>>>(offsets, esrt, x, aggr0);
    layer_gemm<13, true><<<(N_NODES + 63) / 64, 64, 0, stream>>>(aggr0, x, Wrel[0], brel[0], Wroot[0], h0);

    // layers 1..3 (din=64)
    float* hin = h0;
    float* hout = h1;
    for (int l = 1; l <= 3; ++l) {
        gather_aggr<64><<<(N_NODES * 64 + 255) / 256, 256, 0, stream>>>(offsets, esrt, hin, aggr);
        layer_gemm<64, true><<<(N_NODES + 63) / 64, 64, 0, stream>>>(aggr, hin, Wrel[l], brel[l], Wroot[l], hout);
        float* t = hin; hin = hout; hout = t;
    }

    // layer 4: project to scalar first, then aggregate scalars + sigmoid
    final_dots<<<(N_NODES + 255) / 256, 256, 0, stream>>>(hin, Wrel[4], Wroot[4], z, root);
    final_aggr<<<(N_NODES + 255) / 256, 256, 0, stream>>>(offsets, esrt, z, root, brel[4], out);
}

// Round 2
// 366.542 us; speedup vs baseline: 1.7561x; 1.7561x over previous
//
#include <hip/hip_runtime.h>
#include <math.h>

#define N_NODES 50000
#define N_EDGES 800000

// ---------------- CSR build ----------------

__global__ void count_kernel(const int* __restrict__ dst, int* __restrict__ counts, int n_edges) {
    int e = blockIdx.x * blockDim.x + threadIdx.x;
    if (e < n_edges) atomicAdd(&counts[dst[e]], 1);
}

__global__ void scan_blocks(const int* __restrict__ in, int* __restrict__ out,
                            int* __restrict__ blocksums, int n) {
    int t = threadIdx.x;
    int i = blockIdx.x * 256 + t;
    int v = (i < n) ? in[i] : 0;
    int lane = t & 63, w = t >> 6;
    int sc = v;
    #pragma unroll
    for (int o = 1; o < 64; o <<= 1) {
        int u = __shfl_up(sc, o, 64);
        if (lane >= o) sc += u;
    }
    __shared__ int wsum[4];
    if (lane == 63) wsum[w] = sc;
    __syncthreads();
    int add = 0;
    #pragma unroll
    for (int j = 0; j < 4; ++j) if (j < w) add += wsum[j];
    if (i < n) out[i] = add + sc - v;
    if (t == 255 && blocksums) blocksums[blockIdx.x] = add + sc;
}

__global__ void scan_add(int* __restrict__ offsets, const int* __restrict__ blockoffs,
                         int* __restrict__ cursor, int n, int total) {
    int i = blockIdx.x * blockDim.x + threadIdx.x;
    if (i < n) {
        int v = offsets[i] + blockoffs[i >> 8];
        offsets[i] = v;
        cursor[i] = v;
    }
    if (i == n) offsets[n] = total;
}

__global__ void fill_kernel(const int* __restrict__ src, const int* __restrict__ dst,
                            const float* __restrict__ ew, int* __restrict__ cursor,
                            int2* __restrict__ esrt, int n_edges) {
    int e = blockIdx.x * blockDim.x + threadIdx.x;
    if (e < n_edges) {
        int p = atomicAdd(&cursor[dst[e]], 1);
        esrt[p] = make_int2(src[e], __float_as_int(ew[e]));
    }
}

// ---------------- aggregation: one wave per dst node, lane = feature, unroll 4 ----------------

template <int DIN>
__global__ void gather_aggr(const int* __restrict__ offs, const int2* __restrict__ esrt,
                            const float* __restrict__ x, float* __restrict__ aggr) {
    int wid = (blockIdx.x * blockDim.x + threadIdx.x) >> 6;
    int lane = threadIdx.x & 63;
    if (wid >= N_NODES) return;
    int beg = offs[wid], end = offs[wid + 1];
    float acc = 0.f;
    int i = beg;
    for (; i + 4 <= end; i += 4) {
        int2 e0 = esrt[i + 0];
        int2 e1 = esrt[i + 1];
        int2 e2 = esrt[i + 2];
        int2 e3 = esrt[i + 3];
        float v0 = (DIN == 64 || lane < DIN) ? x[(size_t)e0.x * DIN + lane] : 0.f;
        float v1 = (DIN == 64 || lane < DIN) ? x[(size_t)e1.x * DIN + lane] : 0.f;
        float v2 = (DIN == 64 || lane < DIN) ? x[(size_t)e2.x * DIN + lane] : 0.f;
        float v3 = (DIN == 64 || lane < DIN) ? x[(size_t)e3.x * DIN + lane] : 0.f;
        acc = fmaf(__int_as_float(e0.y), v0, acc);
        acc = fmaf(__int_as_float(e1.y), v1, acc);
        acc = fmaf(__int_as_float(e2.y), v2, acc);
        acc = fmaf(__int_as_float(e3.y), v3, acc);
    }
    for (; i < end; ++i) {
        int2 e = esrt[i];
        float v = (DIN == 64 || lane < DIN) ? x[(size_t)e.x * DIN + lane] : 0.f;
        acc = fmaf(__int_as_float(e.y), v, acc);
    }
    if (DIN == 64 || lane < DIN) aggr[(size_t)wid * DIN + lane] = acc;
}

// ---------------- fused dual-GEMM + bias + relu, register-resident weights ----------------
// lane = output column c. Each lane holds Wrel[:,c] and Wroot[:,c] in VGPRs.
// Row activations read coalesced (lane k holds elem k), broadcast via v_readlane (VALU pipe).

__device__ __forceinline__ float bcast(float v, int k) {
    return __int_as_float(__builtin_amdgcn_readlane(__float_as_int(v), k));
}

template <int DIN, bool RELU>
__launch_bounds__(256, 2)
__global__ void layer_gemm(const float* __restrict__ aggr, const float* __restrict__ hin,
                           const float* __restrict__ Wrel, const float* __restrict__ bias,
                           const float* __restrict__ Wroot, float* __restrict__ hout,
                           int rows_per_wave) {
    int lane = threadIdx.x & 63;
    int wid = (blockIdx.x * blockDim.x + threadIdx.x) >> 6;

    float wr[DIN], wo[DIN];
    #pragma unroll
    for (int k = 0; k < DIN; ++k) {
        wr[k] = Wrel[k * 64 + lane];
        wo[k] = Wroot[k * 64 + lane];
    }
    float bc = bias[lane];

    int r0 = wid * rows_per_wave;
    int r1 = min(r0 + rows_per_wave, N_NODES);
    for (int r = r0; r < r1; ++r) {
        float av = (DIN == 64 || lane < DIN) ? aggr[(size_t)r * DIN + lane] : 0.f;
        float hv = (DIN == 64 || lane < DIN) ? hin[(size_t)r * DIN + lane] : 0.f;
        float acc0 = bc, acc1 = 0.f, acc2 = 0.f, acc3 = 0.f;
        #pragma unroll
        for (int k = 0; k + 2 <= DIN; k += 2) {
            acc0 = fmaf(bcast(av, k), wr[k], acc0);
            acc1 = fmaf(bcast(hv, k), wo[k], acc1);
            acc2 = fmaf(bcast(av, k + 1), wr[k + 1], acc2);
            acc3 = fmaf(bcast(hv, k + 1), wo[k + 1], acc3);
        }
        if (DIN & 1) {
            acc0 = fmaf(bcast(av, DIN - 1), wr[DIN - 1], acc0);
            acc1 = fmaf(bcast(hv, DIN - 1), wo[DIN - 1], acc1);
        }
        float o = (acc0 + acc2) + (acc1 + acc3);
        if (RELU) o = fmaxf(o, 0.f);
        hout[(size_t)r * 64 + lane] = o;
    }
}

// ---------------- final layer ----------------

__global__ void final_dots(const float* __restrict__ h, const float* __restrict__ Wrel4,
                           const float* __restrict__ Wroot4, float* __restrict__ z,
                           float* __restrict__ root) {
    __shared__ float wr[64], wo[64];
    if (threadIdx.x < 64) {
        wr[threadIdx.x] = Wrel4[threadIdx.x];
        wo[threadIdx.x] = Wroot4[threadIdx.x];
    }
    __syncthreads();
    int r = blockIdx.x * blockDim.x + threadIdx.x;
    if (r >= N_NODES) return;
    const float4* hrow = (const float4*)(h + (size_t)r * 64);
    float zz = 0.f, rr = 0.f;
    #pragma unroll
    for (int k4 = 0; k4 < 16; ++k4) {
        float4 hv = hrow[k4];
        zz += hv.x * wr[4 * k4 + 0] + hv.y * wr[4 * k4 + 1] + hv.z * wr[4 * k4 + 2] + hv.w * wr[4 * k4 + 3];
        rr += hv.x * wo[4 * k4 + 0] + hv.y * wo[4 * k4 + 1] + hv.z * wo[4 * k4 + 2] + hv.w * wo[4 * k4 + 3];
    }
    z[r] = zz;
    root[r] = rr;
}

__global__ void final_aggr(const int* __restrict__ offs, const int2* __restrict__ esrt,
                           const float* __restrict__ z, const float* __restrict__ root,
                           const float* __restrict__ b4, float* __restrict__ out) {
    int d = blockIdx.x * blockDim.x + threadIdx.x;
    if (d >= N_NODES) return;
    float a = 0.f;
    int beg = offs[d], end = offs[d + 1];
    int i = beg;
    for (; i + 4 <= end; i += 4) {
        int2 e0 = esrt[i + 0], e1 = esrt[i + 1], e2 = esrt[i + 2], e3 = esrt[i + 3];
        float z0 = z[e0.x], z1 = z[e1.x], z2 = z[e2.x], z3 = z[e3.x];
        a = fmaf(__int_as_float(e0.y), z0, a);
        a = fmaf(__int_as_float(e1.y), z1, a);
        a = fmaf(__int_as_float(e2.y), z2, a);
        a = fmaf(__int_as_float(e3.y), z3, a);
    }
    for (; i < end; ++i) {
        int2 e = esrt[i];
        a = fmaf(__int_as_float(e.y), z[e.x], a);
    }
    float v = a + b4[0] + root[d];
    out[d] = 1.f / (1.f + expf(-v));
}

// ---------------- launch ----------------

extern "C" void kernel_launch(void* const* d_in, const int* in_sizes, int n_in,
                              void* d_out, int out_size, void* d_ws, size_t ws_size,
                              hipStream_t stream) {
    const float* x = (const float*)d_in[0];
    const int* eidx = (const int*)d_in[1];
    const float* ew = (const float*)d_in[2];
    const float* Wrel[5];
    const float* brel[5];
    const float* Wroot[5];
    for (int i = 0; i < 5; ++i) {
        Wrel[i] = (const float*)d_in[3 + 3 * i];
        brel[i] = (const float*)d_in[4 + 3 * i];
        Wroot[i] = (const float*)d_in[5 + 3 * i];
    }
    const int* src = eidx;
    const int* dst = eidx + N_EDGES;
    float* out = (float*)d_out;

    char* ws = (char*)d_ws;
    size_t off = 0;
    auto alloc = [&](size_t bytes) -> void* {
        void* p = ws + off;
        off = (off + bytes + 255) & ~(size_t)255;
        return p;
    };
    int* counts = (int*)alloc(N_NODES * 4);
    int* offsets = (int*)alloc((N_NODES + 1) * 4);
    int* cursor = (int*)alloc(N_NODES * 4);
    int* blocksums = (int*)alloc(256 * 4);
    int* blockoffs = (int*)alloc(256 * 4);
    int2* esrt = (int2*)alloc((size_t)N_EDGES * 8);
    float* aggr0 = (float*)alloc((size_t)N_NODES * 13 * 4);
    float* h0 = (float*)alloc((size_t)N_NODES * 64 * 4);
    float* h1 = (float*)alloc((size_t)N_NODES * 64 * 4);
    float* aggr = (float*)alloc((size_t)N_NODES * 64 * 4);
    float* z = (float*)alloc(N_NODES * 4);
    float* root = (float*)alloc(N_NODES * 4);
    (void)ws_size; (void)in_sizes; (void)n_in; (void)out_size;

    // CSR build
    hipMemsetAsync(counts, 0, N_NODES * 4, stream);
    count_kernel<<<(N_EDGES + 255) / 256, 256, 0, stream>>>(dst, counts, N_EDGES);
    const int NB = (N_NODES + 255) / 256;  // 196
    scan_blocks<<<NB, 256, 0, stream>>>(counts, offsets, blocksums, N_NODES);
    scan_blocks<<<1, 256, 0, stream>>>(blocksums, blockoffs, nullptr, NB);
    scan_add<<<(N_NODES + 1 + 255) / 256, 256, 0, stream>>>(offsets, blockoffs, cursor, N_NODES, N_EDGES);
    fill_kernel<<<(N_EDGES + 255) / 256, 256, 0, stream>>>(src, dst, ew, cursor, esrt, N_EDGES);

    const int RPW = 16;                      // rows per wave in layer_gemm
    const int WAVES = (N_NODES + RPW - 1) / RPW;
    const int GB = (WAVES + 3) / 4;          // 4 waves per 256-thread block

    // layer 0 (din=13)
    gather_aggr<13><<<(N_NODES * 64 + 255) / 256, 256, 0, stream>>>(offsets, esrt, x, aggr0);
    layer_gemm<13, true><<<GB, 256, 0, stream>>>(aggr0, x, Wrel[0], brel[0], Wroot[0], h0, RPW);

    // layers 1..3 (din=64)
    float* hin = h0;
    float* hout = h1;
    for (int l = 1; l <= 3; ++l) {
        gather_aggr<64><<<(N_NODES * 64 + 255) / 256, 256, 0, stream>>>(offsets, esrt, hin, aggr);
        layer_gemm<64, true><<<GB, 256, 0, stream>>>(aggr, hin, Wrel[l], brel[l], Wroot[l], hout, RPW);
        float* t = hin; hin = hout; hout = t;
    }

    // layer 4: project to scalar first, then aggregate scalars + sigmoid
    final_dots<<<(N_NODES + 255) / 256, 256, 0, stream>>>(hin, Wrel[4], Wroot[4], z, root);
    final_aggr<<<(N_NODES + 255) / 256, 256, 0, stream>>>(offsets, esrt, z, root, brel[4], out);
}

// Round 3
// 294.922 us; speedup vs baseline: 2.1825x; 1.2428x over previous
//
#include <hip/hip_runtime.h>
#include <math.h>

#define N_NODES 50000
#define N_EDGES 800000
#define NBUCKET 196   // ceil(50000/256), bucket = dst>>8
#define NCHUNK 98     // ceil(800000/8192)
#define CHUNK 8192
#define SCAN_N (NBUCKET * NCHUNK)  // 19208
#define CAP_FINE 6144

// ---------------- sort pass 1: per-chunk coarse histogram ----------------

__global__ void hist_kernel(const int* __restrict__ dst, int* __restrict__ h) {
    __shared__ int hist[NBUCKET];
    for (int i = threadIdx.x; i < NBUCKET; i += 256) hist[i] = 0;
    __syncthreads();
    int base = blockIdx.x * CHUNK;
    int n = min(CHUNK, N_EDGES - base);
    for (int k = threadIdx.x; k < n; k += 256)
        atomicAdd(&hist[dst[base + k] >> 8], 1);
    __syncthreads();
    for (int i = threadIdx.x; i < NBUCKET; i += 256)
        h[i * NCHUNK + blockIdx.x] = hist[i];
}

// ---------------- hierarchical exclusive scan (reused) ----------------

__global__ void scan_blocks(const int* __restrict__ in, int* __restrict__ out,
                            int* __restrict__ blocksums, int n) {
    int t = threadIdx.x;
    int i = blockIdx.x * 256 + t;
    int v = (i < n) ? in[i] : 0;
    int lane = t & 63, w = t >> 6;
    int sc = v;
    #pragma unroll
    for (int o = 1; o < 64; o <<= 1) {
        int u = __shfl_up(sc, o, 64);
        if (lane >= o) sc += u;
    }
    __shared__ int wsum[4];
    if (lane == 63) wsum[w] = sc;
    __syncthreads();
    int add = 0;
    #pragma unroll
    for (int j = 0; j < 4; ++j) if (j < w) add += wsum[j];
    if (i < n) out[i] = add + sc - v;
    if (t == 255 && blocksums) blocksums[blockIdx.x] = add + sc;
}

__global__ void scan_add(int* __restrict__ offsets, const int* __restrict__ blockoffs,
                         int* __restrict__ cursor, int n, int total) {
    int i = blockIdx.x * blockDim.x + threadIdx.x;
    if (i < n) {
        int v = offsets[i] + blockoffs[i >> 8];
        offsets[i] = v;
        if (cursor) cursor[i] = v;
    }
    if (i == n) offsets[n] = total;
}

// ---------------- sort pass 2: coarse scatter (run-coalesced writes) ----------------
// record: x = (dst&255)<<16 | src  (src<50000 fits 16 bits), y = edge weight bits

__global__ void scatter_coarse(const int* __restrict__ src, const int* __restrict__ dst,
                               const float* __restrict__ ew, const int* __restrict__ hs,
                               int2* __restrict__ ecoarse) {
    __shared__ int cur[NBUCKET];
    for (int i = threadIdx.x; i < NBUCKET; i += 256)
        cur[i] = hs[i * NCHUNK + blockIdx.x];
    __syncthreads();
    int base = blockIdx.x * CHUNK;
    int n = min(CHUNK, N_EDGES - base);
    for (int k = threadIdx.x; k < n; k += 256) {
        int e = base + k;
        int d = dst[e];
        int p = atomicAdd(&cur[d >> 8], 1);
        ecoarse[p] = make_int2(((d & 255) << 16) | src[e], __float_as_int(ew[e]));
    }
}

// ---------------- sort pass 3: per-bucket fine sort + CSR offsets ----------------

__launch_bounds__(256)
__global__ void fine_sort(const int* __restrict__ hs, const int2* __restrict__ ecoarse,
                          int2* __restrict__ esrt, int* __restrict__ offs) {
    int b = blockIdx.x;
    int bstart = hs[b * NCHUNK];
    int bend = (b == NBUCKET - 1) ? N_EDGES : hs[(b + 1) * NCHUNK];
    int nb = bend - bstart;
    __shared__ int hist[256], excl[256], cur[256];
    __shared__ int wsum[4];
    __shared__ int2 stage[CAP_FINE];
    hist[threadIdx.x] = 0;
    __syncthreads();
    for (int k = threadIdx.x; k < nb; k += 256)
        atomicAdd(&hist[ecoarse[bstart + k].x >> 16], 1);
    __syncthreads();
    {   // exclusive scan of hist[256]
        int t = threadIdx.x, lane = t & 63, w = t >> 6;
        int v = hist[t], sc = v;
        #pragma unroll
        for (int o = 1; o < 64; o <<= 1) {
            int u = __shfl_up(sc, o, 64);
            if (lane >= o) sc += u;
        }
        if (lane == 63) wsum[w] = sc;
        __syncthreads();
        int add = 0;
        #pragma unroll
        for (int j = 0; j < 4; ++j) if (j < w) add += wsum[j];
        excl[t] = add + sc - v;
        cur[t] = add + sc - v;
    }
    __syncthreads();
    if (nb <= CAP_FINE) {
        for (int k = threadIdx.x; k < nb; k += 256) {
            int2 r = ecoarse[bstart + k];
            int p = atomicAdd(&cur[r.x >> 16], 1);
            stage[p] = make_int2(r.x & 0xFFFF, r.y);
        }
        __syncthreads();
        for (int k = threadIdx.x; k < nb; k += 256)
            esrt[bstart + k] = stage[k];
    } else {  // overflow fallback (never expected for this graph)
        for (int k = threadIdx.x; k < nb; k += 256) {
            int2 r = ecoarse[bstart + k];
            int p = atomicAdd(&cur[r.x >> 16], 1);
            esrt[bstart + p] = make_int2(r.x & 0xFFFF, r.y);
        }
    }
    int dstv = (b << 8) + threadIdx.x;
    if (dstv < N_NODES) offs[dstv] = bstart + excl[threadIdx.x];
    if (b == 0 && threadIdx.x == 0) offs[N_NODES] = N_EDGES;
}

// ---------------- aggregation DIN=64: quarter-wave float4, 4 edges per load ----------------

__launch_bounds__(256)
__global__ void gather_aggr64(const int* __restrict__ offs, const int2* __restrict__ esrt,
                              const float* __restrict__ x, float* __restrict__ aggr) {
    int wid = (blockIdx.x * blockDim.x + threadIdx.x) >> 6;
    if (wid >= N_NODES) return;
    int lane = threadIdx.x & 63;
    int q = lane >> 4, f4 = lane & 15;
    int beg = offs[wid], end = offs[wid + 1];
    float4 acc = make_float4(0.f, 0.f, 0.f, 0.f);
    int i = beg + q;
    for (; i + 4 < end; i += 8) {
        int2 e0 = esrt[i];
        int2 e1 = esrt[i + 4];
        float4 v0 = ((const float4*)(x + (size_t)e0.x * 64))[f4];
        float4 v1 = ((const float4*)(x + (size_t)e1.x * 64))[f4];
        float w0 = __int_as_float(e0.y), w1 = __int_as_float(e1.y);
        acc.x = fmaf(w0, v0.x, acc.x); acc.y = fmaf(w0, v0.y, acc.y);
        acc.z = fmaf(w0, v0.z, acc.z); acc.w = fmaf(w0, v0.w, acc.w);
        acc.x = fmaf(w1, v1.x, acc.x); acc.y = fmaf(w1, v1.y, acc.y);
        acc.z = fmaf(w1, v1.z, acc.z); acc.w = fmaf(w1, v1.w, acc.w);
    }
    if (i < end) {
        int2 e = esrt[i];
        float4 v = ((const float4*)(x + (size_t)e.x * 64))[f4];
        float w = __int_as_float(e.y);
        acc.x = fmaf(w, v.x, acc.x); acc.y = fmaf(w, v.y, acc.y);
        acc.z = fmaf(w, v.z, acc.z); acc.w = fmaf(w, v.w, acc.w);
    }
    acc.x += __shfl_xor(acc.x, 16, 64); acc.y += __shfl_xor(acc.y, 16, 64);
    acc.z += __shfl_xor(acc.z, 16, 64); acc.w += __shfl_xor(acc.w, 16, 64);
    acc.x += __shfl_xor(acc.x, 32, 64); acc.y += __shfl_xor(acc.y, 32, 64);
    acc.z += __shfl_xor(acc.z, 32, 64); acc.w += __shfl_xor(acc.w, 32, 64);
    if (q == 0) ((float4*)(aggr + (size_t)wid * 64))[f4] = acc;
}

// ---------------- aggregation DIN=13 (layer 0 only) ----------------

__global__ void gather_aggr13(const int* __restrict__ offs, const int2* __restrict__ esrt,
                              const float* __restrict__ x, float* __restrict__ aggr) {
    int wid = (blockIdx.x * blockDim.x + threadIdx.x) >> 6;
    int lane = threadIdx.x & 63;
    if (wid >= N_NODES) return;
    int beg = offs[wid], end = offs[wid + 1];
    float acc = 0.f;
    int i = beg;
    for (; i + 4 <= end; i += 4) {
        int2 e0 = esrt[i + 0], e1 = esrt[i + 1], e2 = esrt[i + 2], e3 = esrt[i + 3];
        float v0 = (lane < 13) ? x[(size_t)e0.x * 13 + lane] : 0.f;
        float v1 = (lane < 13) ? x[(size_t)e1.x * 13 + lane] : 0.f;
        float v2 = (lane < 13) ? x[(size_t)e2.x * 13 + lane] : 0.f;
        float v3 = (lane < 13) ? x[(size_t)e3.x * 13 + lane] : 0.f;
        acc = fmaf(__int_as_float(e0.y), v0, acc);
        acc = fmaf(__int_as_float(e1.y), v1, acc);
        acc = fmaf(__int_as_float(e2.y), v2, acc);
        acc = fmaf(__int_as_float(e3.y), v3, acc);
    }
    for (; i < end; ++i) {
        int2 e = esrt[i];
        float v = (lane < 13) ? x[(size_t)e.x * 13 + lane] : 0.f;
        acc = fmaf(__int_as_float(e.y), v, acc);
    }
    if (lane < 13) aggr[(size_t)wid * 13 + lane] = acc;
}

// ---------------- fused dual-GEMM + bias + relu, register-resident weights ----------------

__device__ __forceinline__ float bcast(float v, int k) {
    return __int_as_float(__builtin_amdgcn_readlane(__float_as_int(v), k));
}

template <int DIN, bool RELU>
__launch_bounds__(256, 2)
__global__ void layer_gemm(const float* __restrict__ aggr, const float* __restrict__ hin,
                           const float* __restrict__ Wrel, const float* __restrict__ bias,
                           const float* __restrict__ Wroot, float* __restrict__ hout,
                           int rows_per_wave) {
    int lane = threadIdx.x & 63;
    int wid = (blockIdx.x * blockDim.x + threadIdx.x) >> 6;

    float wr[DIN], wo[DIN];
    #pragma unroll
    for (int k = 0; k < DIN; ++k) {
        wr[k] = Wrel[k * 64 + lane];
        wo[k] = Wroot[k * 64 + lane];
    }
    float bc = bias[lane];

    int r0 = wid * rows_per_wave;
    int r1 = min(r0 + rows_per_wave, N_NODES);
    for (int r = r0; r < r1; ++r) {
        float av = (DIN == 64 || lane < DIN) ? aggr[(size_t)r * DIN + lane] : 0.f;
        float hv = (DIN == 64 || lane < DIN) ? hin[(size_t)r * DIN + lane] : 0.f;
        float acc0 = bc, acc1 = 0.f, acc2 = 0.f, acc3 = 0.f;
        #pragma unroll
        for (int k = 0; k + 2 <= DIN; k += 2) {
            acc0 = fmaf(bcast(av, k), wr[k], acc0);
            acc1 = fmaf(bcast(hv, k), wo[k], acc1);
            acc2 = fmaf(bcast(av, k + 1), wr[k + 1], acc2);
            acc3 = fmaf(bcast(hv, k + 1), wo[k + 1], acc3);
        }
        if (DIN & 1) {
            acc0 = fmaf(bcast(av, DIN - 1), wr[DIN - 1], acc0);
            acc1 = fmaf(bcast(hv, DIN - 1), wo[DIN - 1], acc1);
        }
        float o = (acc0 + acc2) + (acc1 + acc3);
        if (RELU) o = fmaxf(o, 0.f);
        hout[(size_t)r * 64 + lane] = o;
    }
}

// ---------------- final layer ----------------

__global__ void final_dots(const float* __restrict__ h, const float* __restrict__ Wrel4,
                           const float* __restrict__ Wroot4, float* __restrict__ z,
                           float* __restrict__ root) {
    __shared__ float wr[64], wo[64];
    if (threadIdx.x < 64) {
        wr[threadIdx.x] = Wrel4[threadIdx.x];
        wo[threadIdx.x] = Wroot4[threadIdx.x];
    }
    __syncthreads();
    int r = blockIdx.x * blockDim.x + threadIdx.x;
    if (r >= N_NODES) return;
    const float4* hrow = (const float4*)(h + (size_t)r * 64);
    float zz = 0.f, rr = 0.f;
    #pragma unroll
    for (int k4 = 0; k4 < 16; ++k4) {
        float4 hv = hrow[k4];
        zz += hv.x * wr[4 * k4 + 0] + hv.y * wr[4 * k4 + 1] + hv.z * wr[4 * k4 + 2] + hv.w * wr[4 * k4 + 3];
        rr += hv.x * wo[4 * k4 + 0] + hv.y * wo[4 * k4 + 1] + hv.z * wo[4 * k4 + 2] + hv.w * wo[4 * k4 + 3];
    }
    z[r] = zz;
    root[r] = rr;
}

__global__ void final_aggr(const int* __restrict__ offs, const int2* __restrict__ esrt,
                           const float* __restrict__ z, const float* __restrict__ root,
                           const float* __restrict__ b4, float* __restrict__ out) {
    int d = blockIdx.x * blockDim.x + threadIdx.x;
    if (d >= N_NODES) return;
    float a = 0.f;
    int beg = offs[d], end = offs[d + 1];
    int i = beg;
    for (; i + 4 <= end; i += 4) {
        int2 e0 = esrt[i + 0], e1 = esrt[i + 1], e2 = esrt[i + 2], e3 = esrt[i + 3];
        float z0 = z[e0.x], z1 = z[e1.x], z2 = z[e2.x], z3 = z[e3.x];
        a = fmaf(__int_as_float(e0.y), z0, a);
        a = fmaf(__int_as_float(e1.y), z1, a);
        a = fmaf(__int_as_float(e2.y), z2, a);
        a = fmaf(__int_as_float(e3.y), z3, a);
    }
    for (; i < end; ++i) {
        int2 e = esrt[i];
        a = fmaf(__int_as_float(e.y), z[e.x], a);
    }
    float v = a + b4[0] + root[d];
    out[d] = 1.f / (1.f + expf(-v));
}

// ---------------- launch ----------------

extern "C" void kernel_launch(void* const* d_in, const int* in_sizes, int n_in,
                              void* d_out, int out_size, void* d_ws, size_t ws_size,
                              hipStream_t stream) {
    const float* x = (const float*)d_in[0];
    const int* eidx = (const int*)d_in[1];
    const float* ew = (const float*)d_in[2];
    const float* Wrel[5];
    const float* brel[5];
    const float* Wroot[5];
    for (int i = 0; i < 5; ++i) {
        Wrel[i] = (const float*)d_in[3 + 3 * i];
        brel[i] = (const float*)d_in[4 + 3 * i];
        Wroot[i] = (const float*)d_in[5 + 3 * i];
    }
    const int* src = eidx;
    const int* dst = eidx + N_EDGES;
    float* out = (float*)d_out;

    char* ws = (char*)d_ws;
    size_t off = 0;
    auto alloc = [&](size_t bytes) -> void* {
        void* p = ws + off;
        off = (off + bytes + 255) & ~(size_t)255;
        return p;
    };
    int* h = (int*)alloc((SCAN_N + 2) * 4);
    int* blocksums = (int*)alloc(256 * 4);
    int* blockoffs = (int*)alloc(256 * 4);
    int* offs = (int*)alloc((N_NODES + 1) * 4);
    int2* esrt = (int2*)alloc((size_t)N_EDGES * 8);
    float* aggr0 = (float*)alloc((size_t)N_NODES * 13 * 4);
    float* h0 = (float*)alloc((size_t)N_NODES * 64 * 4);
    float* h1 = (float*)alloc((size_t)N_NODES * 64 * 4);
    float* aggr = (float*)alloc((size_t)N_NODES * 64 * 4);
    float* z = (float*)alloc(N_NODES * 4);
    float* root = (float*)alloc(N_NODES * 4);
    int2* ecoarse = (int2*)aggr;  // disjoint lifetime: ecoarse dead before aggr first written
    (void)ws_size; (void)in_sizes; (void)n_in; (void)out_size;

    // CSR build via 2-pass counting sort (all-coalesced writes)
    hist_kernel<<<NCHUNK, 256, 0, stream>>>(dst, h);
    const int SB = (SCAN_N + 255) / 256;  // 76
    scan_blocks<<<SB, 256, 0, stream>>>(h, h, blocksums, SCAN_N);
    scan_blocks<<<1, 256, 0, stream>>>(blocksums, blockoffs, nullptr, SB);
    scan_add<<<SB, 256, 0, stream>>>(h, blockoffs, nullptr, SCAN_N, N_EDGES);
    scatter_coarse<<<NCHUNK, 256, 0, stream>>>(src, dst, ew, h, ecoarse);
    fine_sort<<<NBUCKET, 256, 0, stream>>>(h, ecoarse, esrt, offs);

    const int RPW = 16;
    const int WAVES = (N_NODES + RPW - 1) / RPW;
    const int GB = (WAVES + 3) / 4;

    // layer 0 (din=13)
    gather_aggr13<<<(N_NODES * 64 + 255) / 256, 256, 0, stream>>>(offs, esrt, x, aggr0);
    layer_gemm<13, true><<<GB, 256, 0, stream>>>(aggr0, x, Wrel[0], brel[0], Wroot[0], h0, RPW);

    // layers 1..3 (din=64)
    float* hin = h0;
    float* hout = h1;
    for (int l = 1; l <= 3; ++l) {
        gather_aggr64<<<(N_NODES * 64 + 255) / 256, 256, 0, stream>>>(offs, esrt, hin, aggr);
        layer_gemm<64, true><<<GB, 256, 0, stream>>>(aggr, hin, Wrel[l], brel[l], Wroot[l], hout, RPW);
        float* t = hin; hin = hout; hout = t;
    }

    // layer 4: project to scalar first, then aggregate scalars + sigmoid
    final_dots<<<(N_NODES + 255) / 256, 256, 0, stream>>>(hin, Wrel[4], Wroot[4], z, root);
    final_aggr<<<(N_NODES + 255) / 256, 256, 0, stream>>>(offs, esrt, z, root, brel[4], out);
}

// Round 4
// 263.203 us; speedup vs baseline: 2.4455x; 1.1205x over previous
//
#include <hip/hip_runtime.h>
#include <math.h>

#define N_NODES 50000
#define N_EDGES 800000
#define NBUCKET 196   // ceil(50000/256), bucket = dst>>8
#define CHUNK 4096
#define NCHUNK 196    // ceil(800000/4096) = 196 (195 full + tail 1280)
#define SCAN_N (NBUCKET * NCHUNK)  // 38416
#define CAP_FINE 6144
#define EPT 16        // edges per thread in scatter_coarse (CHUNK/256)

// ---------------- sort pass 1: per-chunk coarse histogram ----------------

__global__ void hist_kernel(const int* __restrict__ dst, int* __restrict__ h) {
    __shared__ int hist[NBUCKET];
    for (int i = threadIdx.x; i < NBUCKET; i += 256) hist[i] = 0;
    __syncthreads();
    int base = blockIdx.x * CHUNK;
    int n = min(CHUNK, N_EDGES - base);
    for (int k = threadIdx.x; k < n; k += 256)
        atomicAdd(&hist[dst[base + k] >> 8], 1);
    __syncthreads();
    for (int i = threadIdx.x; i < NBUCKET; i += 256)
        h[i * NCHUNK + blockIdx.x] = hist[i];
}

// ---------------- hierarchical exclusive scan ----------------

__global__ void scan_blocks(const int* __restrict__ in, int* __restrict__ out,
                            int* __restrict__ blocksums, int n) {
    int t = threadIdx.x;
    int i = blockIdx.x * 256 + t;
    int v = (i < n) ? in[i] : 0;
    int lane = t & 63, w = t >> 6;
    int sc = v;
    #pragma unroll
    for (int o = 1; o < 64; o <<= 1) {
        int u = __shfl_up(sc, o, 64);
        if (lane >= o) sc += u;
    }
    __shared__ int wsum[4];
    if (lane == 63) wsum[w] = sc;
    __syncthreads();
    int add = 0;
    #pragma unroll
    for (int j = 0; j < 4; ++j) if (j < w) add += wsum[j];
    if (i < n) out[i] = add + sc - v;
    if (t == 255 && blocksums) blocksums[blockIdx.x] = add + sc;
}

__global__ void scan_add(int* __restrict__ offsets, const int* __restrict__ blockoffs,
                         int n, int total) {
    int i = blockIdx.x * blockDim.x + threadIdx.x;
    if (i < n) offsets[i] += blockoffs[i >> 8];
    if (i == n) offsets[n] = total;
}

// ---------------- sort pass 2: register-staged LDS bucket sort, coalesced flush ----------------
// record: x = dst<<16 | src (both < 65536), y = weight bits. bucket = (uint)x >> 24.

__launch_bounds__(256, 4)
__global__ void scatter_coarse(const int* __restrict__ src, const int* __restrict__ dst,
                               const float* __restrict__ ew, const int* __restrict__ hs,
                               int2* __restrict__ ecoarse) {
    __shared__ int cnt[NBUCKET];
    __shared__ int excl[NBUCKET];
    __shared__ int cur[NBUCKET];
    __shared__ int gbase[NBUCKET];
    __shared__ int wsum[4];
    __shared__ int2 stage[CHUNK];

    int t = threadIdx.x;
    int base = blockIdx.x * CHUNK;
    int n = min(CHUNK, N_EDGES - base);

    for (int i = t; i < NBUCKET; i += 256) {
        cnt[i] = 0;
        gbase[i] = hs[i * NCHUNK + blockIdx.x];
    }
    __syncthreads();

    // load records to registers + count buckets
    int rx[EPT];
    float rw[EPT];
    #pragma unroll
    for (int j = 0; j < EPT; ++j) {
        int k = t + j * 256;
        if (k < n) {
            int e = base + k;
            int d = dst[e];
            rx[j] = (d << 16) | src[e];
            rw[j] = ew[e];
            atomicAdd(&cnt[d >> 8], 1);
        }
    }
    __syncthreads();

    // exclusive scan over cnt[196] (single 256-thread block scan)
    {
        int v = (t < NBUCKET) ? cnt[t] : 0;
        int lane = t & 63, w = t >> 6;
        int sc = v;
        #pragma unroll
        for (int o = 1; o < 64; o <<= 1) {
            int u = __shfl_up(sc, o, 64);
            if (lane >= o) sc += u;
        }
        if (lane == 63) wsum[w] = sc;
        __syncthreads();
        int add = 0;
        #pragma unroll
        for (int j = 0; j < 4; ++j) if (j < w) add += wsum[j];
        if (t < NBUCKET) {
            excl[t] = add + sc - v;
            cur[t] = add + sc - v;
        }
    }
    __syncthreads();

    // LDS scatter (bucket-sort within chunk)
    #pragma unroll
    for (int j = 0; j < EPT; ++j) {
        int k = t + j * 256;
        if (k < n) {
            int b = ((unsigned)rx[j]) >> 24;
            int p = atomicAdd(&cur[b], 1);
            stage[p] = make_int2(rx[j], __float_as_int(rw[j]));
        }
    }
    __syncthreads();

    // coalesced flush: stage is bucket-ordered; consecutive k -> consecutive global pos
    for (int k = t; k < n; k += 256) {
        int2 r = stage[k];
        int b = ((unsigned)r.x) >> 24;
        ecoarse[gbase[b] + (k - excl[b])] = r;
    }
}

// ---------------- sort pass 3: per-bucket fine sort + CSR offsets ----------------

__launch_bounds__(256)
__global__ void fine_sort(const int* __restrict__ hs, const int2* __restrict__ ecoarse,
                          int2* __restrict__ esrt, int* __restrict__ offs) {
    int b = blockIdx.x;
    int bstart = hs[b * NCHUNK];
    int bend = (b == NBUCKET - 1) ? N_EDGES : hs[(b + 1) * NCHUNK];
    int nb = bend - bstart;
    __shared__ int hist[256], excl[256], cur[256];
    __shared__ int wsum[4];
    __shared__ int2 stage[CAP_FINE];
    hist[threadIdx.x] = 0;
    __syncthreads();
    for (int k = threadIdx.x; k < nb; k += 256)
        atomicAdd(&hist[(((unsigned)ecoarse[bstart + k].x) >> 16) & 255], 1);
    __syncthreads();
    {
        int t = threadIdx.x, lane = t & 63, w = t >> 6;
        int v = hist[t], sc = v;
        #pragma unroll
        for (int o = 1; o < 64; o <<= 1) {
            int u = __shfl_up(sc, o, 64);
            if (lane >= o) sc += u;
        }
        if (lane == 63) wsum[w] = sc;
        __syncthreads();
        int add = 0;
        #pragma unroll
        for (int j = 0; j < 4; ++j) if (j < w) add += wsum[j];
        excl[t] = add + sc - v;
        cur[t] = add + sc - v;
    }
    __syncthreads();
    if (nb <= CAP_FINE) {
        for (int k = threadIdx.x; k < nb; k += 256) {
            int2 r = ecoarse[bstart + k];
            int p = atomicAdd(&cur[(((unsigned)r.x) >> 16) & 255], 1);
            stage[p] = make_int2(r.x & 0xFFFF, r.y);
        }
        __syncthreads();
        for (int k = threadIdx.x; k < nb; k += 256)
            esrt[bstart + k] = stage[k];
    } else {
        for (int k = threadIdx.x; k < nb; k += 256) {
            int2 r = ecoarse[bstart + k];
            int p = atomicAdd(&cur[(((unsigned)r.x) >> 16) & 255], 1);
            esrt[bstart + p] = make_int2(r.x & 0xFFFF, r.y);
        }
    }
    int dstv = (b << 8) + threadIdx.x;
    if (dstv < N_NODES) offs[dstv] = bstart + excl[threadIdx.x];
    if (b == 0 && threadIdx.x == 0) offs[N_NODES] = N_EDGES;
}

// ---------------- aggregation DIN=64: quarter-wave float4, 16 edges in flight ----------------

__launch_bounds__(256)
__global__ void gather_aggr64(const int* __restrict__ offs, const int2* __restrict__ esrt,
                              const float* __restrict__ x, float* __restrict__ aggr) {
    int wid = (blockIdx.x * blockDim.x + threadIdx.x) >> 6;
    if (wid >= N_NODES) return;
    int lane = threadIdx.x & 63;
    int q = lane >> 4, f4 = lane & 15;
    int beg = offs[wid], end = offs[wid + 1];
    float4 acc = make_float4(0.f, 0.f, 0.f, 0.f);
    int i = beg + q;
    for (; i + 12 < end; i += 16) {
        int2 e0 = esrt[i];
        int2 e1 = esrt[i + 4];
        int2 e2 = esrt[i + 8];
        int2 e3 = esrt[i + 12];
        float4 v0 = ((const float4*)(x + (size_t)e0.x * 64))[f4];
        float4 v1 = ((const float4*)(x + (size_t)e1.x * 64))[f4];
        float4 v2 = ((const float4*)(x + (size_t)e2.x * 64))[f4];
        float4 v3 = ((const float4*)(x + (size_t)e3.x * 64))[f4];
        float w0 = __int_as_float(e0.y), w1 = __int_as_float(e1.y);
        float w2 = __int_as_float(e2.y), w3 = __int_as_float(e3.y);
        acc.x = fmaf(w0, v0.x, acc.x); acc.y = fmaf(w0, v0.y, acc.y);
        acc.z = fmaf(w0, v0.z, acc.z); acc.w = fmaf(w0, v0.w, acc.w);
        acc.x = fmaf(w1, v1.x, acc.x); acc.y = fmaf(w1, v1.y, acc.y);
        acc.z = fmaf(w1, v1.z, acc.z); acc.w = fmaf(w1, v1.w, acc.w);
        acc.x = fmaf(w2, v2.x, acc.x); acc.y = fmaf(w2, v2.y, acc.y);
        acc.z = fmaf(w2, v2.z, acc.z); acc.w = fmaf(w2, v2.w, acc.w);
        acc.x = fmaf(w3, v3.x, acc.x); acc.y = fmaf(w3, v3.y, acc.y);
        acc.z = fmaf(w3, v3.z, acc.z); acc.w = fmaf(w3, v3.w, acc.w);
    }
    for (; i + 4 < end; i += 8) {
        int2 e0 = esrt[i];
        int2 e1 = esrt[i + 4];
        float4 v0 = ((const float4*)(x + (size_t)e0.x * 64))[f4];
        float4 v1 = ((const float4*)(x + (size_t)e1.x * 64))[f4];
        float w0 = __int_as_float(e0.y), w1 = __int_as_float(e1.y);
        acc.x = fmaf(w0, v0.x, acc.x); acc.y = fmaf(w0, v0.y, acc.y);
        acc.z = fmaf(w0, v0.z, acc.z); acc.w = fmaf(w0, v0.w, acc.w);
        acc.x = fmaf(w1, v1.x, acc.x); acc.y = fmaf(w1, v1.y, acc.y);
        acc.z = fmaf(w1, v1.z, acc.z); acc.w = fmaf(w1, v1.w, acc.w);
    }
    if (i < end) {
        int2 e = esrt[i];
        float4 v = ((const float4*)(x + (size_t)e.x * 64))[f4];
        float w = __int_as_float(e.y);
        acc.x = fmaf(w, v.x, acc.x); acc.y = fmaf(w, v.y, acc.y);
        acc.z = fmaf(w, v.z, acc.z); acc.w = fmaf(w, v.w, acc.w);
    }
    acc.x += __shfl_xor(acc.x, 16, 64); acc.y += __shfl_xor(acc.y, 16, 64);
    acc.z += __shfl_xor(acc.z, 16, 64); acc.w += __shfl_xor(acc.w, 16, 64);
    acc.x += __shfl_xor(acc.x, 32, 64); acc.y += __shfl_xor(acc.y, 32, 64);
    acc.z += __shfl_xor(acc.z, 32, 64); acc.w += __shfl_xor(acc.w, 32, 64);
    if (q == 0) ((float4*)(aggr + (size_t)wid * 64))[f4] = acc;
}

// ---------------- aggregation DIN=13: 16-lane groups, 4 edges per load instr ----------------

__launch_bounds__(256)
__global__ void gather_aggr13(const int* __restrict__ offs, const int2* __restrict__ esrt,
                              const float* __restrict__ x, float* __restrict__ aggr) {
    int wid = (blockIdx.x * blockDim.x + threadIdx.x) >> 6;
    if (wid >= N_NODES) return;
    int lane = threadIdx.x & 63;
    int q = lane >> 4, f = lane & 15;
    int beg = offs[wid], end = offs[wid + 1];
    float acc = 0.f;
    int i = beg + q;
    for (; i + 4 < end; i += 8) {
        int2 e0 = esrt[i];
        int2 e1 = esrt[i + 4];
        float v0 = (f < 13) ? x[(size_t)e0.x * 13 + f] : 0.f;
        float v1 = (f < 13) ? x[(size_t)e1.x * 13 + f] : 0.f;
        acc = fmaf(__int_as_float(e0.y), v0, acc);
        acc = fmaf(__int_as_float(e1.y), v1, acc);
    }
    if (i < end) {
        int2 e = esrt[i];
        float v = (f < 13) ? x[(size_t)e.x * 13 + f] : 0.f;
        acc = fmaf(__int_as_float(e.y), v, acc);
    }
    acc += __shfl_xor(acc, 16, 64);
    acc += __shfl_xor(acc, 32, 64);
    if (q == 0 && f < 13) aggr[(size_t)wid * 13 + f] = acc;
}

// ---------------- fused dual-GEMM + bias + relu, register-resident weights ----------------

__device__ __forceinline__ float bcast(float v, int k) {
    return __int_as_float(__builtin_amdgcn_readlane(__float_as_int(v), k));
}

template <int DIN, bool RELU>
__launch_bounds__(256, 2)
__global__ void layer_gemm(const float* __restrict__ aggr, const float* __restrict__ hin,
                           const float* __restrict__ Wrel, const float* __restrict__ bias,
                           const float* __restrict__ Wroot, float* __restrict__ hout,
                           int rows_per_wave) {
    int lane = threadIdx.x & 63;
    int wid = (blockIdx.x * blockDim.x + threadIdx.x) >> 6;

    float wr[DIN], wo[DIN];
    #pragma unroll
    for (int k = 0; k < DIN; ++k) {
        wr[k] = Wrel[k * 64 + lane];
        wo[k] = Wroot[k * 64 + lane];
    }
    float bc = bias[lane];

    int r0 = wid * rows_per_wave;
    int r1 = min(r0 + rows_per_wave, N_NODES);
    for (int r = r0; r < r1; ++r) {
        float av = (DIN == 64 || lane < DIN) ? aggr[(size_t)r * DIN + lane] : 0.f;
        float hv = (DIN == 64 || lane < DIN) ? hin[(size_t)r * DIN + lane] : 0.f;
        float acc0 = bc, acc1 = 0.f, acc2 = 0.f, acc3 = 0.f;
        #pragma unroll
        for (int k = 0; k + 2 <= DIN; k += 2) {
            acc0 = fmaf(bcast(av, k), wr[k], acc0);
            acc1 = fmaf(bcast(hv, k), wo[k], acc1);
            acc2 = fmaf(bcast(av, k + 1), wr[k + 1], acc2);
            acc3 = fmaf(bcast(hv, k + 1), wo[k + 1], acc3);
        }
        if (DIN & 1) {
            acc0 = fmaf(bcast(av, DIN - 1), wr[DIN - 1], acc0);
            acc1 = fmaf(bcast(hv, DIN - 1), wo[DIN - 1], acc1);
        }
        float o = (acc0 + acc2) + (acc1 + acc3);
        if (RELU) o = fmaxf(o, 0.f);
        hout[(size_t)r * 64 + lane] = o;
    }
}

// ---------------- final layer ----------------

__global__ void final_dots(const float* __restrict__ h, const float* __restrict__ Wrel4,
                           const float* __restrict__ Wroot4, float* __restrict__ z,
                           float* __restrict__ root) {
    __shared__ float wr[64], wo[64];
    if (threadIdx.x < 64) {
        wr[threadIdx.x] = Wrel4[threadIdx.x];
        wo[threadIdx.x] = Wroot4[threadIdx.x];
    }
    __syncthreads();
    int r = blockIdx.x * blockDim.x + threadIdx.x;
    if (r >= N_NODES) return;
    const float4* hrow = (const float4*)(h + (size_t)r * 64);
    float zz = 0.f, rr = 0.f;
    #pragma unroll
    for (int k4 = 0; k4 < 16; ++k4) {
        float4 hv = hrow[k4];
        zz += hv.x * wr[4 * k4 + 0] + hv.y * wr[4 * k4 + 1] + hv.z * wr[4 * k4 + 2] + hv.w * wr[4 * k4 + 3];
        rr += hv.x * wo[4 * k4 + 0] + hv.y * wo[4 * k4 + 1] + hv.z * wo[4 * k4 + 2] + hv.w * wo[4 * k4 + 3];
    }
    z[r] = zz;
    root[r] = rr;
}

__global__ void final_aggr(const int* __restrict__ offs, const int2* __restrict__ esrt,
                           const float* __restrict__ z, const float* __restrict__ root,
                           const float* __restrict__ b4, float* __restrict__ out) {
    int d = blockIdx.x * blockDim.x + threadIdx.x;
    if (d >= N_NODES) return;
    float a = 0.f;
    int beg = offs[d], end = offs[d + 1];
    int i = beg;
    for (; i + 4 <= end; i += 4) {
        int2 e0 = esrt[i + 0], e1 = esrt[i + 1], e2 = esrt[i + 2], e3 = esrt[i + 3];
        float z0 = z[e0.x], z1 = z[e1.x], z2 = z[e2.x], z3 = z[e3.x];
        a = fmaf(__int_as_float(e0.y), z0, a);
        a = fmaf(__int_as_float(e1.y), z1, a);
        a = fmaf(__int_as_float(e2.y), z2, a);
        a = fmaf(__int_as_float(e3.y), z3, a);
    }
    for (; i < end; ++i) {
        int2 e = esrt[i];
        a = fmaf(__int_as_float(e.y), z[e.x], a);
    }
    float v = a + b4[0] + root[d];
    out[d] = 1.f / (1.f + expf(-v));
}

// ---------------- launch ----------------

extern "C" void kernel_launch(void* const* d_in, const int* in_sizes, int n_in,
                              void* d_out, int out_size, void* d_ws, size_t ws_size,
                              hipStream_t stream) {
    const float* x = (const float*)d_in[0];
    const int* eidx = (const int*)d_in[1];
    const float* ew = (const float*)d_in[2];
    const float* Wrel[5];
    const float* brel[5];
    const float* Wroot[5];
    for (int i = 0; i < 5; ++i) {
        Wrel[i] = (const float*)d_in[3 + 3 * i];
        brel[i] = (const float*)d_in[4 + 3 * i];
        Wroot[i] = (const float*)d_in[5 + 3 * i];
    }
    const int* src = eidx;
    const int* dst = eidx + N_EDGES;
    float* out = (float*)d_out;

    char* ws = (char*)d_ws;
    size_t off = 0;
    auto alloc = [&](size_t bytes) -> void* {
        void* p = ws + off;
        off = (off + bytes + 255) & ~(size_t)255;
        return p;
    };
    int* h = (int*)alloc((SCAN_N + 2) * 4);
    int* blocksums = (int*)alloc(256 * 4);
    int* blockoffs = (int*)alloc(256 * 4);
    int* offs = (int*)alloc((N_NODES + 1) * 4);
    int2* esrt = (int2*)alloc((size_t)N_EDGES * 8);
    float* aggr0 = (float*)alloc((size_t)N_NODES * 13 * 4);
    float* h0 = (float*)alloc((size_t)N_NODES * 64 * 4);
    float* h1 = (float*)alloc((size_t)N_NODES * 64 * 4);
    float* aggr = (float*)alloc((size_t)N_NODES * 64 * 4);
    float* z = (float*)alloc(N_NODES * 4);
    float* root = (float*)alloc(N_NODES * 4);
    int2* ecoarse = (int2*)aggr;  // disjoint lifetime: ecoarse dead before aggr first written
    (void)ws_size; (void)in_sizes; (void)n_in; (void)out_size;

    // CSR build via 2-pass counting sort (all-coalesced global writes)
    hist_kernel<<<NCHUNK, 256, 0, stream>>>(dst, h);
    const int SB = (SCAN_N + 255) / 256;  // 151
    scan_blocks<<<SB, 256, 0, stream>>>(h, h, blocksums, SCAN_N);
    scan_blocks<<<1, 256, 0, stream>>>(blocksums, blockoffs, nullptr, SB);
    scan_add<<<SB, 256, 0, stream>>>(h, blockoffs, SCAN_N, N_EDGES);
    scatter_coarse<<<NCHUNK, 256, 0, stream>>>(src, dst, ew, h, ecoarse);
    fine_sort<<<NBUCKET, 256, 0, stream>>>(h, ecoarse, esrt, offs);

    const int RPW = 16;
    const int WAVES = (N_NODES + RPW - 1) / RPW;
    const int GB = (WAVES + 3) / 4;

    // layer 0 (din=13)
    gather_aggr13<<<(N_NODES * 64 + 255) / 256, 256, 0, stream>>>(offs, esrt, x, aggr0);
    layer_gemm<13, true><<<GB, 256, 0, stream>>>(aggr0, x, Wrel[0], brel[0], Wroot[0], h0, RPW);

    // layers 1..3 (din=64)
    float* hin = h0;
    float* hout = h1;
    for (int l = 1; l <= 3; ++l) {
        gather_aggr64<<<(N_NODES * 64 + 255) / 256, 256, 0, stream>>>(offs, esrt, hin, aggr);
        layer_gemm<64, true><<<GB, 256, 0, stream>>>(aggr, hin, Wrel[l], brel[l], Wroot[l], hout, RPW);
        float* t = hin; hin = hout; hout = t;
    }

    // layer 4: project to scalar first, then aggregate scalars + sigmoid
    final_dots<<<(N_NODES + 255) / 256, 256, 0, stream>>>(hin, Wrel[4], Wroot[4], z, root);
    final_aggr<<<(N_NODES + 255) / 256, 256, 0, stream>>>(offs, esrt, z, root, brel[4], out);
}